// Round 15
// baseline (131.826 us; speedup 1.0000x reference)
//
#include <hip/hip_runtime.h>
#include <math.h>

#define B_   8
#define C_   64
#define CK_  8
#define L_   4096

typedef __attribute__((ext_vector_type(8))) __bf16 bf16x8;
typedef __attribute__((ext_vector_type(4))) __bf16 bf16x4;
typedef __attribute__((ext_vector_type(4))) float  f32x4;

// ---------------- Kernel 1: QKV projection -> bf16 ----------------
// (byte-identical to the r14 hardware-verified version: LDS-staged x tile)
__global__ __launch_bounds__(256) void qkv_kernel(
    const float* __restrict__ x,
    const float* __restrict__ Wq, const float* __restrict__ bq,
    const float* __restrict__ Wk, const float* __restrict__ bk,
    const float* __restrict__ Wv, const float* __restrict__ bv,
    __bf16* __restrict__ qo, __bf16* __restrict__ ko, __bf16* __restrict__ vpack)
{
    __shared__ float LWq[CK_ * C_];
    __shared__ float LWk[CK_ * C_];
    __shared__ float LWv[C_ * C_];      // row-major [c_out][c_in]
    __shared__ float LX[64][68];        // x tile [c][l], pad 68
    __shared__ __bf16 Lqs[64 * 8];
    __shared__ __bf16 Lks[64 * 8];

    const int tid = threadIdx.x;
    const int b  = blockIdx.x >> 6;
    const int t  = blockIdx.x & 63;
    const int l0 = t << 6;

    if (tid < 128) {
        ((float4*)LWq)[tid] = ((const float4*)Wq)[tid];
        ((float4*)LWk)[tid] = ((const float4*)Wk)[tid];
    }
    #pragma unroll
    for (int j = 0; j < 4; ++j)
        ((float4*)LWv)[tid + j * 256] = ((const float4*)Wv)[tid + j * 256];
    {   // stage x tile
        const int c = tid >> 2, part = tid & 3;
        const float* xrow = x + ((size_t)b * C_ + c) * L_ + l0 + part * 16;
        float4* dst = (float4*)&LX[c][part * 16];
        #pragma unroll
        for (int u = 0; u < 4; ++u) dst[u] = ((const float4*)xrow)[u];
    }
    __syncthreads();

    const int lg = tid & 15;
    const int g  = tid >> 4;

    float va[4][4];
    float qk[4];
    #pragma unroll
    for (int j = 0; j < 4; ++j) {
        float bb = bv[4 * g + j];
        va[j][0] = bb; va[j][1] = bb; va[j][2] = bb; va[j][3] = bb;
    }
    {
        float bb = (g < 8) ? bq[g] : bk[g - 8];
        qk[0] = bb; qk[1] = bb; qk[2] = bb; qk[3] = bb;
    }
    const float* wqk = (g < 8) ? (LWq + g * C_) : (LWk + (g - 8) * C_);

    #pragma unroll 4
    for (int c4 = 0; c4 < 16; ++c4) {
        float4 xv[4];
        #pragma unroll
        for (int u = 0; u < 4; ++u)
            xv[u] = *(const float4*)&LX[4 * c4 + u][lg * 4];
        #pragma unroll
        for (int j = 0; j < 4; ++j) {
            float4 wv = ((const float4*)(LWv + (4 * g + j) * C_))[c4];
            float* a = va[j];
            a[0]=fmaf(wv.x,xv[0].x,a[0]); a[1]=fmaf(wv.x,xv[0].y,a[1]); a[2]=fmaf(wv.x,xv[0].z,a[2]); a[3]=fmaf(wv.x,xv[0].w,a[3]);
            a[0]=fmaf(wv.y,xv[1].x,a[0]); a[1]=fmaf(wv.y,xv[1].y,a[1]); a[2]=fmaf(wv.y,xv[1].z,a[2]); a[3]=fmaf(wv.y,xv[1].w,a[3]);
            a[0]=fmaf(wv.z,xv[2].x,a[0]); a[1]=fmaf(wv.z,xv[2].y,a[1]); a[2]=fmaf(wv.z,xv[2].z,a[2]); a[3]=fmaf(wv.z,xv[2].w,a[3]);
            a[0]=fmaf(wv.w,xv[3].x,a[0]); a[1]=fmaf(wv.w,xv[3].y,a[1]); a[2]=fmaf(wv.w,xv[3].z,a[2]); a[3]=fmaf(wv.w,xv[3].w,a[3]);
        }
        {
            float4 wv = ((const float4*)wqk)[c4];
            qk[0]=fmaf(wv.x,xv[0].x,qk[0]); qk[1]=fmaf(wv.x,xv[0].y,qk[1]); qk[2]=fmaf(wv.x,xv[0].z,qk[2]); qk[3]=fmaf(wv.x,xv[0].w,qk[3]);
            qk[0]=fmaf(wv.y,xv[1].x,qk[0]); qk[1]=fmaf(wv.y,xv[1].y,qk[1]); qk[2]=fmaf(wv.y,xv[1].z,qk[2]); qk[3]=fmaf(wv.y,xv[1].w,qk[3]);
            qk[0]=fmaf(wv.z,xv[2].x,qk[0]); qk[1]=fmaf(wv.z,xv[2].y,qk[1]); qk[2]=fmaf(wv.z,xv[2].z,qk[2]); qk[3]=fmaf(wv.z,xv[2].w,qk[3]);
            qk[0]=fmaf(wv.w,xv[3].x,qk[0]); qk[1]=fmaf(wv.w,xv[3].y,qk[1]); qk[2]=fmaf(wv.w,xv[3].z,qk[2]); qk[3]=fmaf(wv.w,xv[3].w,qk[3]);
        }
    }

    // vpack stores (identical layout)
    {
        __bf16* vt = vpack + ((size_t)b * 64 + t) * 4096;
        const int cb = g >> 2;
        const int sg = lg >> 2;
        const int qd = lg & 3;
        #pragma unroll
        for (int j = 0; j < 4; ++j) {
            bf16x4 vv;
            vv[0]=(__bf16)va[j][0]; vv[1]=(__bf16)va[j][1]; vv[2]=(__bf16)va[j][2]; vv[3]=(__bf16)va[j][3];
            *(bf16x4*)(vt + ((size_t)((cb * 4 + sg) * 64 + qd * 16 + (g & 3) * 4 + j)) * 4) = vv;
        }
    }
    #pragma unroll
    for (int u = 0; u < 4; ++u) {
        if (g < 8) Lqs[(lg * 4 + u) * 8 + g]       = (__bf16)qk[u];
        else       Lks[(lg * 4 + u) * 8 + (g - 8)] = (__bf16)qk[u];
    }
    __syncthreads();
    if (tid < 64) {
        *(bf16x8*)(qo + ((size_t)b * L_ + l0 + tid) * 8) = *(bf16x8*)(Lqs + tid * 8);
        *(bf16x8*)(ko + ((size_t)b * L_ + l0 + tid) * 8) = *(bf16x8*)(Lks + tid * 8);
    }
}

// ---------------- Kernel 2: attention phase-1, l-split partials -----------
// grid: B*64*2 = 1024 blocks x 512 thr = 524288 threads = 32 waves/CU (was
// 16). Block (b, mb, lq) covers l in [lq*2048, +2048): 16 tiles/lh-half,
// 8 pair-iterations. Single-buffered 32KB LDS (r13-verified barrier pattern)
// -> 4 blocks/CU fit. Per-wave register/code shape identical to r12 (VGPR 64,
// no spill). Writes unnormalized partial acc (bf16 [c][m]) + colsum.
__global__ __launch_bounds__(512, 4) void attn_kernel(
    const __bf16* __restrict__ q, const __bf16* __restrict__ kT,
    const __bf16* __restrict__ VP,
    __bf16* __restrict__ pacc, float* __restrict__ pcs)
{
    __shared__ __bf16 Lv[4][4096];      // 32 KB single buffer
    __shared__ float  csA[8][16];

    const int tid  = threadIdx.x;
    const int w    = tid >> 6;
    const int lane = tid & 63;
    const int quad = lane >> 4;
    const int l16  = lane & 15;
    const int wh   = w & 3;
    const int lh   = w >> 2;
    const int wg   = blockIdx.x;
    const int b    = wg & 7;            // XCD swizzle (bijective: 1024%8==0)
    const int mb   = (wg >> 3) & 63;
    const int lq   = wg >> 9;           // l-half of the batch
    const int m0   = mb << 6;

    const __bf16* vp = VP + (size_t)b * (64 * 4096);
    const __bf16* qb = q  + (size_t)b * L_ * CK_;

    bf16x8 kf = {};
    if (quad == 0) kf = *(const bf16x8*)(kT + ((size_t)b * L_ + m0 + wh * 16 + l16) * CK_);

    // staging shares: u = w*4+k: tl = u>>3 (lh-half = tl&1, parity = tl>>1),
    // seg = u&7. Global tile for slot tl at iter i: lq*32 + (tl&1)*16 + 2i + (tl>>1)
    const __bf16* gk[4];
    int ok[4];
    #pragma unroll
    for (int k = 0; k < 4; ++k) {
        const int u = w * 4 + k, tl = u >> 3, seg = u & 7;
        gk[k] = vp + (size_t)(lq * 32 + (tl & 1) * 16 + (tl >> 1)) * 4096 + seg * 512 + lane * 8;
        ok[k] = tl * 4096 + seg * 512 + lane * 8;
    }

    f32x4 acc[4] = {};
    float csum = 0.f;
    bf16x8 r[4];

    // prologue: stage iter 0
    #pragma unroll
    for (int k = 0; k < 4; ++k) r[k] = *(const bf16x8*)gk[k];
    #pragma unroll
    for (int k = 0; k < 4; ++k) *(bf16x8*)(&Lv[0][0] + ok[k]) = r[k];

    for (int i = 0; i < 8; ++i) {
        __syncthreads();    // publish ds_writes (prologue or prev iter end)

        if (i < 7) {        // issue next-iter V loads early (land under compute)
            #pragma unroll
            for (int k = 0; k < 4; ++k)
                r[k] = *(const bf16x8*)(gk[k] + (size_t)(i + 1) * 8192);
        }

        const int te = lq * 32 + lh * 16 + 2 * i;   // even tile of this pair
        bf16x8 qA[4], qB[4];
        #pragma unroll
        for (int sg = 0; sg < 4; ++sg) {
            qA[sg] = *(const bf16x8*)(qb + (size_t)(te * 64 + sg * 16 + l16) * CK_);
            qB[sg] = *(const bf16x8*)(qb + (size_t)((te + 1) * 64 + sg * 16 + l16) * CK_);
        }

        bf16x4 pkA[4], pkB[4];
        #pragma unroll
        for (int sg = 0; sg < 4; ++sg) {
            f32x4 sv = __builtin_amdgcn_mfma_f32_16x16x32_bf16(qA[sg], kf, (f32x4){0.f,0.f,0.f,0.f}, 0, 0, 0);
            const float e0 = __expf(sv[0]);
            const float e1 = __expf(sv[1]);
            const float e2 = __expf(sv[2]);
            const float e3 = __expf(sv[3]);
            csum += (e0 + e1) + (e2 + e3);
            pkA[sg][0]=(__bf16)e0; pkA[sg][1]=(__bf16)e1; pkA[sg][2]=(__bf16)e2; pkA[sg][3]=(__bf16)e3;
        }
        #pragma unroll
        for (int sg = 0; sg < 4; ++sg) {
            f32x4 sv = __builtin_amdgcn_mfma_f32_16x16x32_bf16(qB[sg], kf, (f32x4){0.f,0.f,0.f,0.f}, 0, 0, 0);
            const float e0 = __expf(sv[0]);
            const float e1 = __expf(sv[1]);
            const float e2 = __expf(sv[2]);
            const float e3 = __expf(sv[3]);
            csum += (e0 + e1) + (e2 + e3);
            pkB[sg][0]=(__bf16)e0; pkB[sg][1]=(__bf16)e1; pkB[sg][2]=(__bf16)e2; pkB[sg][3]=(__bf16)e3;
        }

        const __bf16* LbA = &Lv[lh][0];
        const __bf16* LbB = &Lv[2 + lh][0];
        #pragma unroll
        for (int sg = 0; sg < 4; ++sg) {
            bf16x8 p8 = __builtin_shufflevector(pkA[sg], pkB[sg], 0, 1, 2, 3, 4, 5, 6, 7);
            #pragma unroll
            for (int cb = 0; cb < 4; ++cb) {
                bf16x4 vfA = *(const bf16x4*)(LbA + ((size_t)((cb * 4 + sg) * 64 + lane)) * 4);
                bf16x4 vfB = *(const bf16x4*)(LbB + ((size_t)((cb * 4 + sg) * 64 + lane)) * 4);
                bf16x8 a8 = __builtin_shufflevector(vfA, vfB, 0, 1, 2, 3, 4, 5, 6, 7);
                acc[cb] = __builtin_amdgcn_mfma_f32_16x16x32_bf16(a8, p8, acc[cb], 0, 0, 0);
            }
        }

        __syncthreads();    // all V reads of this iter done
        if (i < 7) {        // overwrite the single buffer for iter i+1
            #pragma unroll
            for (int k = 0; k < 4; ++k)
                *(bf16x8*)(&Lv[0][0] + ok[k]) = r[k];
        }
    }

    // ---- epilogue: reduce lh=1 into lh=0, write partial acc + colsum ----
    // Last loop barrier ended all V reads; Lv reusable as Sc (16 KB).
    float* Sc = (float*)&Lv[0][0];
    if (lh == 1) {
        #pragma unroll
        for (int cb = 0; cb < 4; ++cb)
            #pragma unroll
            for (int r2 = 0; r2 < 4; ++r2)
                Sc[(wh * 64 + cb * 16 + quad * 4 + r2) * 16 + l16] = acc[cb][r2];
    }
    csum += __shfl_xor(csum, 16);
    csum += __shfl_xor(csum, 32);
    if (quad == 0) csA[w][l16] = csum;
    __syncthreads();

    const size_t pbase = ((size_t)(b * 64 + mb)) * 2 + lq;
    if (lh == 0) {
        if (quad == 0)
            pcs[pbase * 64 + wh * 16 + l16] = csA[wh][l16] + csA[wh + 4][l16];
        __bf16* pa = pacc + pbase * 4096;
        #pragma unroll
        for (int cb = 0; cb < 4; ++cb) {
            #pragma unroll
            for (int r2 = 0; r2 < 4; ++r2) {
                const int c = cb * 16 + quad * 4 + r2;
                const float vsum = acc[cb][r2] + Sc[(wh * 64 + c) * 16 + l16];
                pa[c * 64 + wh * 16 + l16] = (__bf16)vsum;
            }
        }
    }
}

// ---------------- Kernel 3: combine partials, normalize, residual ---------
// (r2-verified structure, NPART=2)
__global__ __launch_bounds__(256) void combine_kernel(
    const __bf16* __restrict__ pacc, const float* __restrict__ pcs,
    const float* __restrict__ x, const float* __restrict__ gamma_p,
    float* __restrict__ out)
{
    const int tid = threadIdx.x;
    const int m  = tid & 63;
    const int cq = tid >> 6;
    const int b  = blockIdx.x >> 6;
    const int mb = blockIdx.x & 63;

    const size_t base = ((size_t)(b * 64 + mb)) * 2;
    const float csv = pcs[base * 64 + m] + pcs[(base + 1) * 64 + m];
    const float rinv = gamma_p[0] / csv;

    const __bf16* pa = pacc + base * 4096;
    #pragma unroll
    for (int ci = 0; ci < 16; ++ci) {
        const int c = cq * 16 + ci;
        const float s = (float)pa[c * 64 + m] + (float)pa[4096 + c * 64 + m];
        const size_t idx = ((size_t)(b * 64 + c)) * L_ + mb * 64 + m;
        out[idx] = fmaf(rinv, s, x[idx]);
    }
}

extern "C" void kernel_launch(void* const* d_in, const int* in_sizes, int n_in,
                              void* d_out, int out_size, void* d_ws, size_t ws_size,
                              hipStream_t stream) {
    const float* x  = (const float*)d_in[0];
    const float* Wq = (const float*)d_in[1];
    const float* bq = (const float*)d_in[2];
    const float* Wk = (const float*)d_in[3];
    const float* bk = (const float*)d_in[4];
    const float* Wv = (const float*)d_in[5];
    const float* bv = (const float*)d_in[6];
    const float* gm = (const float*)d_in[7];
    float* out = (float*)d_out;

    __bf16* ws    = (__bf16*)d_ws;
    __bf16* qo    = ws;                         // 262144 bf16
    __bf16* ko    = ws + 262144;                // 262144 bf16
    __bf16* vpack = ws + 524288;                // 2097152 bf16
    __bf16* pacc  = ws + 2621440;               // 1024*4096 = 4194304 bf16
    float*  pcs   = (float*)(ws + 6815744);     // 1024*64 f32

    qkv_kernel<<<dim3(B_ * (L_ / 64)), dim3(256), 0, stream>>>(
        x, Wq, bq, Wk, bk, Wv, bv, qo, ko, vpack);
    attn_kernel<<<dim3(B_ * 64 * 2), dim3(512), 0, stream>>>(
        qo, ko, vpack, pacc, pcs);
    combine_kernel<<<dim3(B_ * 64), dim3(256), 0, stream>>>(
        pacc, pcs, x, gm, out);
}

// Round 17
// 119.080 us; speedup vs baseline: 1.1070x; 1.1070x over previous
//
#include <hip/hip_runtime.h>
#include <math.h>

#define B_   8
#define C_   64
#define CK_  8
#define L_   4096

typedef __attribute__((ext_vector_type(8))) __bf16 bf16x8;
typedef __attribute__((ext_vector_type(4))) __bf16 bf16x4;
typedef __attribute__((ext_vector_type(4))) float  f32x4;

// ---------------- Kernel 1: QKV projection -> bf16 ----------------
// r14-verified (LDS-staged x tile). ONE delta: vpack is stored PAIR-
// INTERLEAVED: for tile-pair T = t>>1, p = t&1, element (row=cb*4+sg,
// slot, p) lives at (b*32+T)*8192 + row*512 + slot*8 + p*4. The two 4-bf16
// p-slots of the same (row,slot) are adjacent, so attn's PV A-fragment
// (tileA||tileB) is a single 16B read.
__global__ __launch_bounds__(256) void qkv_kernel(
    const float* __restrict__ x,
    const float* __restrict__ Wq, const float* __restrict__ bq,
    const float* __restrict__ Wk, const float* __restrict__ bk,
    const float* __restrict__ Wv, const float* __restrict__ bv,
    __bf16* __restrict__ qo, __bf16* __restrict__ ko, __bf16* __restrict__ vpack)
{
    __shared__ float LWq[CK_ * C_];
    __shared__ float LWk[CK_ * C_];
    __shared__ float LWv[C_ * C_];      // row-major [c_out][c_in]
    __shared__ float LX[64][68];        // x tile [c][l], pad 68
    __shared__ __bf16 Lqs[64 * 8];
    __shared__ __bf16 Lks[64 * 8];

    const int tid = threadIdx.x;
    const int b  = blockIdx.x >> 6;
    const int t  = blockIdx.x & 63;
    const int l0 = t << 6;

    if (tid < 128) {
        ((float4*)LWq)[tid] = ((const float4*)Wq)[tid];
        ((float4*)LWk)[tid] = ((const float4*)Wk)[tid];
    }
    #pragma unroll
    for (int j = 0; j < 4; ++j)
        ((float4*)LWv)[tid + j * 256] = ((const float4*)Wv)[tid + j * 256];
    {   // stage x tile
        const int c = tid >> 2, part = tid & 3;
        const float* xrow = x + ((size_t)b * C_ + c) * L_ + l0 + part * 16;
        float4* dst = (float4*)&LX[c][part * 16];
        #pragma unroll
        for (int u = 0; u < 4; ++u) dst[u] = ((const float4*)xrow)[u];
    }
    __syncthreads();

    const int lg = tid & 15;
    const int g  = tid >> 4;

    float va[4][4];
    float qk[4];
    #pragma unroll
    for (int j = 0; j < 4; ++j) {
        float bb = bv[4 * g + j];
        va[j][0] = bb; va[j][1] = bb; va[j][2] = bb; va[j][3] = bb;
    }
    {
        float bb = (g < 8) ? bq[g] : bk[g - 8];
        qk[0] = bb; qk[1] = bb; qk[2] = bb; qk[3] = bb;
    }
    const float* wqk = (g < 8) ? (LWq + g * C_) : (LWk + (g - 8) * C_);

    #pragma unroll 4
    for (int c4 = 0; c4 < 16; ++c4) {
        float4 xv[4];
        #pragma unroll
        for (int u = 0; u < 4; ++u)
            xv[u] = *(const float4*)&LX[4 * c4 + u][lg * 4];
        #pragma unroll
        for (int j = 0; j < 4; ++j) {
            float4 wv = ((const float4*)(LWv + (4 * g + j) * C_))[c4];
            float* a = va[j];
            a[0]=fmaf(wv.x,xv[0].x,a[0]); a[1]=fmaf(wv.x,xv[0].y,a[1]); a[2]=fmaf(wv.x,xv[0].z,a[2]); a[3]=fmaf(wv.x,xv[0].w,a[3]);
            a[0]=fmaf(wv.y,xv[1].x,a[0]); a[1]=fmaf(wv.y,xv[1].y,a[1]); a[2]=fmaf(wv.y,xv[1].z,a[2]); a[3]=fmaf(wv.y,xv[1].w,a[3]);
            a[0]=fmaf(wv.z,xv[2].x,a[0]); a[1]=fmaf(wv.z,xv[2].y,a[1]); a[2]=fmaf(wv.z,xv[2].z,a[2]); a[3]=fmaf(wv.z,xv[2].w,a[3]);
            a[0]=fmaf(wv.w,xv[3].x,a[0]); a[1]=fmaf(wv.w,xv[3].y,a[1]); a[2]=fmaf(wv.w,xv[3].z,a[2]); a[3]=fmaf(wv.w,xv[3].w,a[3]);
        }
        {
            float4 wv = ((const float4*)wqk)[c4];
            qk[0]=fmaf(wv.x,xv[0].x,qk[0]); qk[1]=fmaf(wv.x,xv[0].y,qk[1]); qk[2]=fmaf(wv.x,xv[0].z,qk[2]); qk[3]=fmaf(wv.x,xv[0].w,qk[3]);
            qk[0]=fmaf(wv.y,xv[1].x,qk[0]); qk[1]=fmaf(wv.y,xv[1].y,qk[1]); qk[2]=fmaf(wv.y,xv[1].z,qk[2]); qk[3]=fmaf(wv.y,xv[1].w,qk[3]);
            qk[0]=fmaf(wv.z,xv[2].x,qk[0]); qk[1]=fmaf(wv.z,xv[2].y,qk[1]); qk[2]=fmaf(wv.z,xv[2].z,qk[2]); qk[3]=fmaf(wv.z,xv[2].w,qk[3]);
            qk[0]=fmaf(wv.w,xv[3].x,qk[0]); qk[1]=fmaf(wv.w,xv[3].y,qk[1]); qk[2]=fmaf(wv.w,xv[3].z,qk[2]); qk[3]=fmaf(wv.w,xv[3].w,qk[3]);
        }
    }

    // vpack stores, pair-interleaved layout
    {
        const int T = t >> 1, p = t & 1;
        __bf16* vt = vpack + ((size_t)(b * 32 + T)) * 8192 + p * 4;
        const int cb = g >> 2;
        const int sg = lg >> 2;
        const int qd = lg & 3;
        #pragma unroll
        for (int j = 0; j < 4; ++j) {
            bf16x4 vv;
            vv[0]=(__bf16)va[j][0]; vv[1]=(__bf16)va[j][1]; vv[2]=(__bf16)va[j][2]; vv[3]=(__bf16)va[j][3];
            *(bf16x4*)(vt + (size_t)((cb * 4 + sg) * 512 + (qd * 16 + (g & 3) * 4 + j) * 8)) = vv;
        }
    }
    #pragma unroll
    for (int u = 0; u < 4; ++u) {
        if (g < 8) Lqs[(lg * 4 + u) * 8 + g]       = (__bf16)qk[u];
        else       Lks[(lg * 4 + u) * 8 + (g - 8)] = (__bf16)qk[u];
    }
    __syncthreads();
    if (tid < 64) {
        *(bf16x8*)(qo + ((size_t)b * L_ + l0 + tid) * 8) = *(bf16x8*)(Lqs + tid * 8);
        *(bf16x8*)(ko + ((size_t)b * L_ + l0 + tid) * 8) = *(bf16x8*)(Lks + tid * 8);
    }
}

// ---------------- Kernel 2: fused attention ------------------------------
// r12/r14 structure with two register-neutral deltas:
// (1) pair-interleaved V in LDS: PV A-frag = ONE ds_read_b128 (16/iter vs
//     32 b64 + 16 merges).
// (2) q staged through LDS with the V staging (dbuf): no per-iter global
//     q loads on the critical path; reads are quad-broadcast b128.
// r16 bug fixed: Lq per-buffer lh-stride is 1024 bf16 (oq used 2048 — the
// GLOBAL row stride — writing past the buffer and corrupting csA -> NaN).
__global__ __launch_bounds__(512, 4) void attn_kernel(
    const __bf16* __restrict__ q, const __bf16* __restrict__ kT,
    const __bf16* __restrict__ VP, const float* __restrict__ x,
    const float* __restrict__ gamma_p, float* __restrict__ out)
{
    __shared__ __bf16 Lv[2][16384];     // 64 KB: [buf][h*8192 + row*512 + lane*8 (+p*4)]
    __shared__ __bf16 Lq[2][2][1024];   // 8 KB:  [buf][lh][part*512 + srow*8]
    __shared__ float  csA[8][16];

    const int tid  = threadIdx.x;
    const int w    = tid >> 6;
    const int lane = tid & 63;
    const int quad = lane >> 4;
    const int l16  = lane & 15;
    const int wh   = w & 3;
    const int lh   = w >> 2;
    const int wg   = blockIdx.x;
    const int b    = wg & 7;            // XCD swizzle
    const int mb   = wg >> 3;
    const int m0   = mb << 6;

    const __bf16* vp2 = VP + (size_t)b * 262144;
    const __bf16* qb  = q  + (size_t)b * L_ * CK_;

    bf16x8 kf = {};
    if (quad == 0) kf = *(const bf16x8*)(kT + ((size_t)b * L_ + m0 + wh * 16 + l16) * CK_);

    // V staging shares: u = w*4+k in [0,32): h = u>>4 (lh-half), s16 = u&15 (row)
    const __bf16* gk[4];
    int ok[4];
    #pragma unroll
    for (int k = 0; k < 4; ++k) {
        const int u = w * 4 + k, h = u >> 4, s16 = u & 15;
        gk[k] = vp2 + (size_t)(h * 16) * 8192 + s16 * 512 + lane * 8;
        ok[k] = h * 8192 + s16 * 512 + lane * 8;
    }
    // q staging share (waves 0-3): lh_q = w>>1, part = w&1; row = lane.
    // Global: lh-half stride = 2048 rows. LDS: lh stride = 1024 bf16 (FIX).
    const __bf16* gq = qb + (size_t)((w >> 1) * 2048 + (w & 1) * 64 + lane) * 8;
    const int oq = (w >> 1) * 1024 + (w & 1) * 512 + lane * 8;

    f32x4 acc[4] = {};
    float csum = 0.f;
    bf16x8 r[4], rq;

    // prologue: stage iter 0 (V + q) into buf0
    #pragma unroll
    for (int k = 0; k < 4; ++k) r[k] = *(const bf16x8*)gk[k];
    if (w < 4) rq = *(const bf16x8*)gq;
    #pragma unroll
    for (int k = 0; k < 4; ++k) *(bf16x8*)(&Lv[0][0] + ok[k]) = r[k];
    if (w < 4) *(bf16x8*)(&Lq[0][0][0] + oq) = rq;

    for (int i = 0; i < 16; ++i) {
        __syncthreads();    // publish buf i&1; all reads of buf (i+1)&1 done

        if (i < 15) {       // issue next-iter loads early (land under compute)
            #pragma unroll
            for (int k = 0; k < 4; ++k)
                r[k] = *(const bf16x8*)(gk[k] + (size_t)(i + 1) * 8192);
            if (w < 4) rq = *(const bf16x8*)(gq + (size_t)(i + 1) * 1024);
        }

        // q from LDS: part0 = tile 2i (A), part1 = tile 2i+1 (B); quad-broadcast
        const __bf16* Lqh = &Lq[i & 1][lh][0];
        bf16x8 qA[4], qB[4];
        #pragma unroll
        for (int sg = 0; sg < 4; ++sg) {
            qA[sg] = *(const bf16x8*)(Lqh + (sg * 16 + l16) * 8);
            qB[sg] = *(const bf16x8*)(Lqh + 512 + (sg * 16 + l16) * 8);
        }

        bf16x4 pkA[4], pkB[4];
        #pragma unroll
        for (int sg = 0; sg < 4; ++sg) {
            f32x4 sv = __builtin_amdgcn_mfma_f32_16x16x32_bf16(qA[sg], kf, (f32x4){0.f,0.f,0.f,0.f}, 0, 0, 0);
            const float e0 = __expf(sv[0]);
            const float e1 = __expf(sv[1]);
            const float e2 = __expf(sv[2]);
            const float e3 = __expf(sv[3]);
            csum += (e0 + e1) + (e2 + e3);
            pkA[sg][0]=(__bf16)e0; pkA[sg][1]=(__bf16)e1; pkA[sg][2]=(__bf16)e2; pkA[sg][3]=(__bf16)e3;
        }
        #pragma unroll
        for (int sg = 0; sg < 4; ++sg) {
            f32x4 sv = __builtin_amdgcn_mfma_f32_16x16x32_bf16(qB[sg], kf, (f32x4){0.f,0.f,0.f,0.f}, 0, 0, 0);
            const float e0 = __expf(sv[0]);
            const float e1 = __expf(sv[1]);
            const float e2 = __expf(sv[2]);
            const float e3 = __expf(sv[3]);
            csum += (e0 + e1) + (e2 + e3);
            pkB[sg][0]=(__bf16)e0; pkB[sg][1]=(__bf16)e1; pkB[sg][2]=(__bf16)e2; pkB[sg][3]=(__bf16)e3;
        }

        const __bf16* Lb = &Lv[i & 1][lh * 8192];
        #pragma unroll
        for (int sg = 0; sg < 4; ++sg) {
            bf16x8 p8 = __builtin_shufflevector(pkA[sg], pkB[sg], 0, 1, 2, 3, 4, 5, 6, 7);
            #pragma unroll
            for (int cb = 0; cb < 4; ++cb) {
                bf16x8 a8 = *(const bf16x8*)(Lb + (size_t)((cb * 4 + sg) * 512 + lane * 8));
                acc[cb] = __builtin_amdgcn_mfma_f32_16x16x32_bf16(a8, p8, acc[cb], 0, 0, 0);
            }
        }

        if (i < 15) {       // write-late into the other buffer
            const int nb = (i + 1) & 1;
            #pragma unroll
            for (int k = 0; k < 4; ++k)
                *(bf16x8*)(&Lv[nb][0] + ok[k]) = r[k];
            if (w < 4) *(bf16x8*)(&Lq[nb][0][0] + oq) = rq;
        }
    }

    // ---- epilogue: reduce lh=1 into lh=0, normalize, residual ----
    // Sc = first 16 KB of Lv buf0; last iter (15) read buf1 only.
    float* Sc = (float*)&Lv[0][0];
    if (lh == 1) {
        #pragma unroll
        for (int cb = 0; cb < 4; ++cb)
            #pragma unroll
            for (int r2 = 0; r2 < 4; ++r2)
                Sc[(wh * 64 + cb * 16 + quad * 4 + r2) * 16 + l16] = acc[cb][r2];
    }
    csum += __shfl_xor(csum, 16);
    csum += __shfl_xor(csum, 32);
    if (quad == 0) csA[w][l16] = csum;
    __syncthreads();

    if (lh == 0) {
        const float rinv = gamma_p[0] / (csA[wh][l16] + csA[wh + 4][l16]);
        #pragma unroll
        for (int cb = 0; cb < 4; ++cb) {
            #pragma unroll
            for (int r2 = 0; r2 < 4; ++r2) {
                const int c = cb * 16 + quad * 4 + r2;
                const float vsum = acc[cb][r2] + Sc[(wh * 64 + c) * 16 + l16];
                const size_t idx = ((size_t)(b * 64 + c)) * L_ + m0 + wh * 16 + l16;
                out[idx] = fmaf(rinv, vsum, x[idx]);
            }
        }
    }
}

extern "C" void kernel_launch(void* const* d_in, const int* in_sizes, int n_in,
                              void* d_out, int out_size, void* d_ws, size_t ws_size,
                              hipStream_t stream) {
    const float* x  = (const float*)d_in[0];
    const float* Wq = (const float*)d_in[1];
    const float* bq = (const float*)d_in[2];
    const float* Wk = (const float*)d_in[3];
    const float* bk = (const float*)d_in[4];
    const float* Wv = (const float*)d_in[5];
    const float* bv = (const float*)d_in[6];
    const float* gm = (const float*)d_in[7];
    float* out = (float*)d_out;

    __bf16* ws    = (__bf16*)d_ws;
    __bf16* qo    = ws;                         // 262144 bf16
    __bf16* ko    = ws + 262144;                // 262144 bf16
    __bf16* vpack = ws + 524288;                // 2097152 bf16

    qkv_kernel<<<dim3(B_ * (L_ / 64)), dim3(256), 0, stream>>>(
        x, Wq, bq, Wk, bk, Wv, bv, qo, ko, vpack);
    attn_kernel<<<dim3(B_ * 64), dim3(512), 0, stream>>>(
        qo, ko, vpack, x, gm, out);
}

// Round 20
// 115.517 us; speedup vs baseline: 1.1412x; 1.0308x over previous
//
#include <hip/hip_runtime.h>
#include <math.h>

#define B_   8
#define C_   64
#define CK_  8
#define L_   4096
#define LOG2E 1.44269504088896f

typedef __attribute__((ext_vector_type(8))) __bf16 bf16x8;
typedef __attribute__((ext_vector_type(4))) __bf16 bf16x4;
typedef __attribute__((ext_vector_type(4))) float  f32x4;

// ---------------- Kernel 1: QKV projection -> bf16 ----------------
// r17-verified (LDS-staged x, pair-interleaved vpack). ONE delta: Wq/bq are
// pre-scaled by log2e while staging, so attn's QK scores arrive in log2
// domain and exp(x) = v_exp_f32 directly (no per-element mul).
__global__ __launch_bounds__(256) void qkv_kernel(
    const float* __restrict__ x,
    const float* __restrict__ Wq, const float* __restrict__ bq,
    const float* __restrict__ Wk, const float* __restrict__ bk,
    const float* __restrict__ Wv, const float* __restrict__ bv,
    __bf16* __restrict__ qo, __bf16* __restrict__ ko, __bf16* __restrict__ vpack)
{
    __shared__ float LWq[CK_ * C_];
    __shared__ float LWk[CK_ * C_];
    __shared__ float LWv[C_ * C_];      // row-major [c_out][c_in]
    __shared__ float LX[64][68];        // x tile [c][l], pad 68
    __shared__ __bf16 Lqs[64 * 8];
    __shared__ __bf16 Lks[64 * 8];

    const int tid = threadIdx.x;
    const int b  = blockIdx.x >> 6;
    const int t  = blockIdx.x & 63;
    const int l0 = t << 6;

    if (tid < 128) {
        float4 a = ((const float4*)Wq)[tid];
        a.x *= LOG2E; a.y *= LOG2E; a.z *= LOG2E; a.w *= LOG2E;
        ((float4*)LWq)[tid] = a;
        ((float4*)LWk)[tid] = ((const float4*)Wk)[tid];
    }
    #pragma unroll
    for (int j = 0; j < 4; ++j)
        ((float4*)LWv)[tid + j * 256] = ((const float4*)Wv)[tid + j * 256];
    {   // stage x tile
        const int c = tid >> 2, part = tid & 3;
        const float* xrow = x + ((size_t)b * C_ + c) * L_ + l0 + part * 16;
        float4* dst = (float4*)&LX[c][part * 16];
        #pragma unroll
        for (int u = 0; u < 4; ++u) dst[u] = ((const float4*)xrow)[u];
    }
    __syncthreads();

    const int lg = tid & 15;
    const int g  = tid >> 4;

    float va[4][4];
    float qk[4];
    #pragma unroll
    for (int j = 0; j < 4; ++j) {
        float bb = bv[4 * g + j];
        va[j][0] = bb; va[j][1] = bb; va[j][2] = bb; va[j][3] = bb;
    }
    {
        float bb = (g < 8) ? bq[g] * LOG2E : bk[g - 8];
        qk[0] = bb; qk[1] = bb; qk[2] = bb; qk[3] = bb;
    }
    const float* wqk = (g < 8) ? (LWq + g * C_) : (LWk + (g - 8) * C_);

    #pragma unroll 4
    for (int c4 = 0; c4 < 16; ++c4) {
        float4 xv[4];
        #pragma unroll
        for (int u = 0; u < 4; ++u)
            xv[u] = *(const float4*)&LX[4 * c4 + u][lg * 4];
        #pragma unroll
        for (int j = 0; j < 4; ++j) {
            float4 wv = ((const float4*)(LWv + (4 * g + j) * C_))[c4];
            float* a = va[j];
            a[0]=fmaf(wv.x,xv[0].x,a[0]); a[1]=fmaf(wv.x,xv[0].y,a[1]); a[2]=fmaf(wv.x,xv[0].z,a[2]); a[3]=fmaf(wv.x,xv[0].w,a[3]);
            a[0]=fmaf(wv.y,xv[1].x,a[0]); a[1]=fmaf(wv.y,xv[1].y,a[1]); a[2]=fmaf(wv.y,xv[1].z,a[2]); a[3]=fmaf(wv.y,xv[1].w,a[3]);
            a[0]=fmaf(wv.z,xv[2].x,a[0]); a[1]=fmaf(wv.z,xv[2].y,a[1]); a[2]=fmaf(wv.z,xv[2].z,a[2]); a[3]=fmaf(wv.z,xv[2].w,a[3]);
            a[0]=fmaf(wv.w,xv[3].x,a[0]); a[1]=fmaf(wv.w,xv[3].y,a[1]); a[2]=fmaf(wv.w,xv[3].z,a[2]); a[3]=fmaf(wv.w,xv[3].w,a[3]);
        }
        {
            float4 wv = ((const float4*)wqk)[c4];
            qk[0]=fmaf(wv.x,xv[0].x,qk[0]); qk[1]=fmaf(wv.x,xv[0].y,qk[1]); qk[2]=fmaf(wv.x,xv[0].z,qk[2]); qk[3]=fmaf(wv.x,xv[0].w,qk[3]);
            qk[0]=fmaf(wv.y,xv[1].x,qk[0]); qk[1]=fmaf(wv.y,xv[1].y,qk[1]); qk[2]=fmaf(wv.y,xv[1].z,qk[2]); qk[3]=fmaf(wv.y,xv[1].w,qk[3]);
            qk[0]=fmaf(wv.z,xv[2].x,qk[0]); qk[1]=fmaf(wv.z,xv[2].y,qk[1]); qk[2]=fmaf(wv.z,xv[2].z,qk[2]); qk[3]=fmaf(wv.z,xv[2].w,qk[3]);
            qk[0]=fmaf(wv.w,xv[3].x,qk[0]); qk[1]=fmaf(wv.w,xv[3].y,qk[1]); qk[2]=fmaf(wv.w,xv[3].z,qk[2]); qk[3]=fmaf(wv.w,xv[3].w,qk[3]);
        }
    }

    // vpack stores, pair-interleaved layout (r17-verified)
    {
        const int T = t >> 1, p = t & 1;
        __bf16* vt = vpack + ((size_t)(b * 32 + T)) * 8192 + p * 4;
        const int cb = g >> 2;
        const int sg = lg >> 2;
        const int qd = lg & 3;
        #pragma unroll
        for (int j = 0; j < 4; ++j) {
            bf16x4 vv;
            vv[0]=(__bf16)va[j][0]; vv[1]=(__bf16)va[j][1]; vv[2]=(__bf16)va[j][2]; vv[3]=(__bf16)va[j][3];
            *(bf16x4*)(vt + (size_t)((cb * 4 + sg) * 512 + (qd * 16 + (g & 3) * 4 + j) * 8)) = vv;
        }
    }
    #pragma unroll
    for (int u = 0; u < 4; ++u) {
        if (g < 8) Lqs[(lg * 4 + u) * 8 + g]       = (__bf16)qk[u];
        else       Lks[(lg * 4 + u) * 8 + (g - 8)] = (__bf16)qk[u];
    }
    __syncthreads();
    if (tid < 64) {
        *(bf16x8*)(qo + ((size_t)b * L_ + l0 + tid) * 8) = *(bf16x8*)(Lqs + tid * 8);
        *(bf16x8*)(ko + ((size_t)b * L_ + l0 + tid) * 8) = *(bf16x8*)(Lks + tid * 8);
    }
}

// ---------------- Kernel 2: fused attention ------------------------------
// r17-verified structure (attn 42us). Deltas: (1) exp via
// __builtin_amdgcn_exp2f on the pre-scaled scores — removes 32 v_mul/iter;
// compiler builtin, so MFMA->VALU hazards are compiler-managed (the r5/r6
// NaN was INLINE-ASM v_exp, not the prescale); (2) p8 filled directly
// per-sg (drops pkA/pkB temporaries + shufflevector merge).
__global__ __launch_bounds__(512, 4) void attn_kernel(
    const __bf16* __restrict__ q, const __bf16* __restrict__ kT,
    const __bf16* __restrict__ VP, const float* __restrict__ x,
    const float* __restrict__ gamma_p, float* __restrict__ out)
{
    __shared__ __bf16 Lv[2][16384];     // 64 KB: [buf][h*8192 + row*512 + lane*8 (+p*4)]
    __shared__ __bf16 Lq[2][2][1024];   // 8 KB:  [buf][lh][part*512 + srow*8]
    __shared__ float  csA[8][16];

    const int tid  = threadIdx.x;
    const int w    = tid >> 6;
    const int lane = tid & 63;
    const int quad = lane >> 4;
    const int l16  = lane & 15;
    const int wh   = w & 3;
    const int lh   = w >> 2;
    const int wg   = blockIdx.x;
    const int b    = wg & 7;            // XCD swizzle
    const int mb   = wg >> 3;
    const int m0   = mb << 6;

    const __bf16* vp2 = VP + (size_t)b * 262144;
    const __bf16* qb  = q  + (size_t)b * L_ * CK_;

    bf16x8 kf = {};
    if (quad == 0) kf = *(const bf16x8*)(kT + ((size_t)b * L_ + m0 + wh * 16 + l16) * CK_);

    // V staging shares: u = w*4+k in [0,32): h = u>>4 (lh-half), s16 = u&15 (row)
    const __bf16* gk[4];
    int ok[4];
    #pragma unroll
    for (int k = 0; k < 4; ++k) {
        const int u = w * 4 + k, h = u >> 4, s16 = u & 15;
        gk[k] = vp2 + (size_t)(h * 16) * 8192 + s16 * 512 + lane * 8;
        ok[k] = h * 8192 + s16 * 512 + lane * 8;
    }
    // q staging share (waves 0-3): lh_q = w>>1, part = w&1; row = lane.
    const __bf16* gq = qb + (size_t)((w >> 1) * 2048 + (w & 1) * 64 + lane) * 8;
    const int oq = (w >> 1) * 1024 + (w & 1) * 512 + lane * 8;

    f32x4 acc[4] = {};
    float csum = 0.f;
    bf16x8 r[4], rq;

    // prologue: stage iter 0 (V + q) into buf0
    #pragma unroll
    for (int k = 0; k < 4; ++k) r[k] = *(const bf16x8*)gk[k];
    if (w < 4) rq = *(const bf16x8*)gq;
    #pragma unroll
    for (int k = 0; k < 4; ++k) *(bf16x8*)(&Lv[0][0] + ok[k]) = r[k];
    if (w < 4) *(bf16x8*)(&Lq[0][0][0] + oq) = rq;

    for (int i = 0; i < 16; ++i) {
        __syncthreads();    // publish buf i&1; all reads of buf (i+1)&1 done

        if (i < 15) {       // issue next-iter loads early (land under compute)
            #pragma unroll
            for (int k = 0; k < 4; ++k)
                r[k] = *(const bf16x8*)(gk[k] + (size_t)(i + 1) * 8192);
            if (w < 4) rq = *(const bf16x8*)(gq + (size_t)(i + 1) * 1024);
        }

        const __bf16* Lqh = &Lq[i & 1][lh][0];
        const __bf16* Lb  = &Lv[i & 1][lh * 8192];
        #pragma unroll
        for (int sg = 0; sg < 4; ++sg) {
            bf16x8 qA = *(const bf16x8*)(Lqh + (sg * 16 + l16) * 8);
            bf16x8 qB = *(const bf16x8*)(Lqh + 512 + (sg * 16 + l16) * 8);
            f32x4 svA = __builtin_amdgcn_mfma_f32_16x16x32_bf16(qA, kf, (f32x4){0.f,0.f,0.f,0.f}, 0, 0, 0);
            f32x4 svB = __builtin_amdgcn_mfma_f32_16x16x32_bf16(qB, kf, (f32x4){0.f,0.f,0.f,0.f}, 0, 0, 0);

            const float eA0 = __builtin_amdgcn_exp2f(svA[0]);
            const float eA1 = __builtin_amdgcn_exp2f(svA[1]);
            const float eA2 = __builtin_amdgcn_exp2f(svA[2]);
            const float eA3 = __builtin_amdgcn_exp2f(svA[3]);
            const float eB0 = __builtin_amdgcn_exp2f(svB[0]);
            const float eB1 = __builtin_amdgcn_exp2f(svB[1]);
            const float eB2 = __builtin_amdgcn_exp2f(svB[2]);
            const float eB3 = __builtin_amdgcn_exp2f(svB[3]);
            csum += ((eA0 + eA1) + (eA2 + eA3)) + ((eB0 + eB1) + (eB2 + eB3));

            bf16x8 p8;
            p8[0]=(__bf16)eA0; p8[1]=(__bf16)eA1; p8[2]=(__bf16)eA2; p8[3]=(__bf16)eA3;
            p8[4]=(__bf16)eB0; p8[5]=(__bf16)eB1; p8[6]=(__bf16)eB2; p8[7]=(__bf16)eB3;

            #pragma unroll
            for (int cb = 0; cb < 4; ++cb) {
                bf16x8 a8 = *(const bf16x8*)(Lb + (size_t)((cb * 4 + sg) * 512 + lane * 8));
                acc[cb] = __builtin_amdgcn_mfma_f32_16x16x32_bf16(a8, p8, acc[cb], 0, 0, 0);
            }
        }

        if (i < 15) {       // write-late into the other buffer
            const int nb = (i + 1) & 1;
            #pragma unroll
            for (int k = 0; k < 4; ++k)
                *(bf16x8*)(&Lv[nb][0] + ok[k]) = r[k];
            if (w < 4) *(bf16x8*)(&Lq[nb][0][0] + oq) = rq;
        }
    }

    // ---- epilogue: reduce lh=1 into lh=0, normalize, residual ----
    // Sc = first 16 KB of Lv buf0; last iter (15) read buf1 only.
    float* Sc = (float*)&Lv[0][0];
    if (lh == 1) {
        #pragma unroll
        for (int cb = 0; cb < 4; ++cb)
            #pragma unroll
            for (int r2 = 0; r2 < 4; ++r2)
                Sc[(wh * 64 + cb * 16 + quad * 4 + r2) * 16 + l16] = acc[cb][r2];
    }
    csum += __shfl_xor(csum, 16);
    csum += __shfl_xor(csum, 32);
    if (quad == 0) csA[w][l16] = csum;
    __syncthreads();

    if (lh == 0) {
        const float rinv = gamma_p[0] / (csA[wh][l16] + csA[wh + 4][l16]);
        #pragma unroll
        for (int cb = 0; cb < 4; ++cb) {
            #pragma unroll
            for (int r2 = 0; r2 < 4; ++r2) {
                const int c = cb * 16 + quad * 4 + r2;
                const float vsum = acc[cb][r2] + Sc[(wh * 64 + c) * 16 + l16];
                const size_t idx = ((size_t)(b * 64 + c)) * L_ + m0 + wh * 16 + l16;
                out[idx] = fmaf(rinv, vsum, x[idx]);
            }
        }
    }
}

extern "C" void kernel_launch(void* const* d_in, const int* in_sizes, int n_in,
                              void* d_out, int out_size, void* d_ws, size_t ws_size,
                              hipStream_t stream) {
    const float* x  = (const float*)d_in[0];
    const float* Wq = (const float*)d_in[1];
    const float* bq = (const float*)d_in[2];
    const float* Wk = (const float*)d_in[3];
    const float* bk = (const float*)d_in[4];
    const float* Wv = (const float*)d_in[5];
    const float* bv = (const float*)d_in[6];
    const float* gm = (const float*)d_in[7];
    float* out = (float*)d_out;

    __bf16* ws    = (__bf16*)d_ws;
    __bf16* qo    = ws;                         // 262144 bf16
    __bf16* ko    = ws + 262144;                // 262144 bf16
    __bf16* vpack = ws + 524288;                // 2097152 bf16

    qkv_kernel<<<dim3(B_ * (L_ / 64)), dim3(256), 0, stream>>>(
        x, Wq, bq, Wk, bk, Wv, bv, qo, ko, vpack);
    attn_kernel<<<dim3(B_ * 64), dim3(512), 0, stream>>>(
        qo, ko, vpack, x, gm, out);
}